// Round 2
// baseline (14271.709 us; speedup 1.0000x reference)
//
#include <hip/hip_runtime.h>
#include <hip/hip_bf16.h>
#include <stdint.h>
#include <math.h>

// ElmoLstm on MI355X — persistent kernel (cooperative, plain-launch fallback).
// L=2 layers x 2 dirs, B=64, T=128, D=H=512, C=4096.
// Per step/dir: gates = [h|x] @ [Wh|Wi]^T + b (bf16 MFMA, fp32 acc),
// LSTM cell w/ clip, h = clip(act @ Wp^T).
// Wh|Wi live in VGPRs (32 rows x K=1024 per wave = 256 VGPRs), Wp in static LDS,
// c-state in registers. Two grid barriers per step via agent-scope atomics.

#define BB 64
#define TT 128
#define DD 512
#define HH 512
#define CC 4096
#define NBLK 256
#define LDS_BYTES 147968  // 131072 Wp + 16896 gt

typedef __bf16 v8bf __attribute__((ext_vector_type(8)));
typedef float  v4f  __attribute__((ext_vector_type(4)));
typedef short  v8s  __attribute__((ext_vector_type(8)));

__device__ __forceinline__ uint16_t f2bf(float f) {
    unsigned int x = __float_as_uint(f);
    unsigned int r = (x + 0x7fffu + ((x >> 16) & 1u)) >> 16;
    return (uint16_t)r;
}
__device__ __forceinline__ float sigm(float x) { return 1.0f / (1.0f + __expf(-x)); }

// ---------------- weight conversion ----------------
// Wf[(l,dir,j)][k] : k<512 -> Wh[(l,dir,j)][k], k>=512 -> Wi[(l,dir,j)][k-512]
__global__ __launch_bounds__(256) void k_conv_wfull(
        const float* __restrict__ Wi, const float* __restrict__ Wh,
        uint16_t* __restrict__ Wf) {
    size_t i   = (size_t)blockIdx.x * blockDim.x + threadIdx.x;
    size_t idx = i * 8;
    size_t row = idx >> 10;
    int    k   = (int)(idx & 1023);
    const float* s = (k < 512) ? (Wh + row * 512 + k) : (Wi + row * 512 + (k - 512));
    float4 f0 = ((const float4*)s)[0];
    float4 f1 = ((const float4*)s)[1];
    v8s v;
    v[0]=f2bf(f0.x); v[1]=f2bf(f0.y); v[2]=f2bf(f0.z); v[3]=f2bf(f0.w);
    v[4]=f2bf(f1.x); v[5]=f2bf(f1.y); v[6]=f2bf(f1.z); v[7]=f2bf(f1.w);
    ((v8s*)Wf)[i] = v;
}

__global__ __launch_bounds__(256) void k_conv_plain(
        const float* __restrict__ src, uint16_t* __restrict__ dst, int n8) {
    int i = blockIdx.x * blockDim.x + threadIdx.x;
    if (i >= n8) return;
    const float4* s = (const float4*)(src + (size_t)i * 8);
    float4 f0 = s[0];
    float4 f1 = s[1];
    v8s v;
    v[0]=f2bf(f0.x); v[1]=f2bf(f0.y); v[2]=f2bf(f0.z); v[3]=f2bf(f0.w);
    v[4]=f2bf(f1.x); v[5]=f2bf(f1.y); v[6]=f2bf(f1.z); v[7]=f2bf(f1.w);
    ((v8s*)dst)[i] = v;
}

// ---------------- init: zero h0 + barrier state (ws may be re-poisoned) ----
__global__ __launch_bounds__(256) void k_init(uint16_t* __restrict__ hbuf,
                                              unsigned* __restrict__ bar) {
    int idx = blockIdx.x * 256 + threadIdx.x;
    if (idx < 8192) ((int4*)hbuf)[idx] = make_int4(0, 0, 0, 0); // 131072 B
    if (blockIdx.x == 0 && threadIdx.x < 64) bar[threadIdx.x] = 0;
}

// ---------------- grid barrier (sense-reversing, agent scope) --------------
__device__ __forceinline__ void gridbar(unsigned* cnt, unsigned* gen) {
    __syncthreads();
    if (threadIdx.x == 0) {
        unsigned g = __hip_atomic_load(gen, __ATOMIC_RELAXED, __HIP_MEMORY_SCOPE_AGENT);
        unsigned a = __hip_atomic_fetch_add(cnt, 1u, __ATOMIC_ACQ_REL, __HIP_MEMORY_SCOPE_AGENT);
        if (a == NBLK - 1u) {
            __hip_atomic_store(cnt, 0u, __ATOMIC_RELAXED, __HIP_MEMORY_SCOPE_AGENT);
            __hip_atomic_fetch_add(gen, 1u, __ATOMIC_ACQ_REL, __HIP_MEMORY_SCOPE_AGENT);
        } else {
            while (__hip_atomic_load(gen, __ATOMIC_RELAXED, __HIP_MEMORY_SCOPE_AGENT) == g)
                __builtin_amdgcn_s_sleep(2);
            __builtin_amdgcn_fence(__ATOMIC_ACQUIRE, "agent");
        }
    }
    __syncthreads();
}

// ---------------- persistent ELMo LSTM ----------------
// 256 blocks x 256 thr. Gates: block (gdir = bx>>7, cells = (bx&127)*32..+32),
// wave w = gate group, 32 rows/wave register-resident over K=1024 = [h|x].
// Proj: XCD-grouped tiles — xcd=bx&7 -> (pdir,pbm), bx>>3 -> pbn; Wp tile in LDS.
__global__ __launch_bounds__(256, 1) void k_elmo(
        const uint16_t* __restrict__ Wf,    // [2][2][16384][1024] bf16
        const float*    __restrict__ bias,  // [2][2][16384]
        const uint16_t* __restrict__ Wpb,   // [2][2][512][4096] bf16
        const uint16_t* __restrict__ xb,    // [64][128][512] bf16
        uint16_t* __restrict__ hseq,        // [2][64][128][512] bf16 (layer0 out)
        uint16_t* __restrict__ hbuf,        // [2][64][512] bf16 (recurrent h)
        uint16_t* __restrict__ actb,        // [2][64][4096] bf16
        float*    __restrict__ out,
        unsigned* __restrict__ bar) {
    const int tid  = threadIdx.x;
    const int w    = tid >> 6;
    const int lane = tid & 63;
    const int col  = lane & 15;
    const int quad = lane >> 4;
    const int bx   = blockIdx.x;
    const int gdir = bx >> 7, cellblk = bx & 127;
    const int xcd  = bx & 7,  rr = bx >> 3;
    const int pdir = xcd >> 2, pbm = xcd & 3, pbn = rr;

    __shared__ __attribute__((aligned(128))) char lds[LDS_BYTES]; // [0,131072): Wp tile
    float (*gt)[32][33] = (float (*)[32][33])(lds + 131072);
    float* red = (float*)(lds + 131072);                // overlays gt (disjoint phases)

    unsigned* cnt = bar;
    unsigned* gen = bar + 32;                           // separate cacheline

    const size_t SEQ = (size_t)BB * TT * 1024;
    float* hs_base = out + 2 * SEQ;
    float* cs_base = hs_base + 2ull * BB * 1024;

    float c_reg[8];
    v8bf  wreg[2][32];                                  // 256 VGPRs of weights

    for (int l = 0; l < 2; ++l) {
        const uint16_t* Wl   = Wf + (size_t)l * 2 * 16384 * 1024;
        const float*    bd   = bias + ((size_t)l * 2 + gdir) * 16384;
        const uint16_t* Wpl  = Wpb + ((size_t)l * 2 + pdir) * 512 * 4096;
        const uint16_t* xsrc = l ? (hseq + (size_t)gdir * BB * TT * HH) : xb;
        float* seq_l = out + (size_t)l * SEQ;
        float* hs_l  = hs_base + (size_t)l * BB * 1024;
        float* cs_l  = cs_base + (size_t)l * BB * 8192;

        // ---- load this wave's gate-weight fragments (once per layer) ----
#pragma unroll
        for (int nt = 0; nt < 2; ++nt) {
            int j = w * 4096 + cellblk * 32 + nt * 16 + col;
            const uint16_t* rp = Wl + ((size_t)gdir * 16384 + j) * 1024 + quad * 8;
#pragma unroll
            for (int ks = 0; ks < 32; ++ks)
                wreg[nt][ks] = *(const v8bf*)(rp + ks * 32);
        }
        // ---- stage Wp tile into LDS, xor-swizzled (once per layer) ----
        for (int c8 = tid; c8 < 8192; c8 += 256) {
            int row = c8 >> 9;              // 512 x 16B chunks per row
            int off = (c8 & 511) << 4;
            const uint16_t* src = Wpl + (size_t)(pbn * 16 + row) * 4096 + (off >> 1);
            v8s v = *(const v8s*)src;
            *(v8s*)(lds + ((row * 8192 + off) ^ ((row & 7) << 4))) = v;
        }
        __syncthreads();

        for (int t = 0; t < TT; ++t) {
            const bool first = (t == 0), last = (t == TT - 1);
            const int gtt = gdir ? (TT - 1 - t) : t;

            // ---- gates: acc[m-tile][n-tile], K = [h(512) | x(512)] ----
            v4f acc[4][2] = {};
            const uint16_t* hA = hbuf + (size_t)gdir * BB * HH;
#pragma unroll
            for (int ks = 0; ks < 32; ++ks) {
                v8bf a[4];
                if (ks < 16) {
                    int k = ks * 32 + quad * 8;
#pragma unroll
                    for (int mt = 0; mt < 4; ++mt)
                        a[mt] = *(const v8bf*)(hA + (size_t)(mt * 16 + col) * HH + k);
                } else {
                    int k = (ks - 16) * 32 + quad * 8;
#pragma unroll
                    for (int mt = 0; mt < 4; ++mt)
                        a[mt] = *(const v8bf*)(xsrc + ((size_t)(mt * 16 + col) * TT + gtt) * DD + k);
                }
#pragma unroll
                for (int mt = 0; mt < 4; ++mt)
#pragma unroll
                    for (int nt = 0; nt < 2; ++nt)
                        acc[mt][nt] = __builtin_amdgcn_mfma_f32_16x16x32_bf16(
                                a[mt], wreg[nt][ks], acc[mt][nt], 0, 0, 0);
            }

            // ---- cell epilogue: two half-passes over m (gt fits beside Wp) ----
#pragma unroll
            for (int p = 0; p < 2; ++p) {
#pragma unroll
                for (int mh = 0; mh < 2; ++mh)
#pragma unroll
                    for (int nt = 0; nt < 2; ++nt)
#pragma unroll
                        for (int r = 0; r < 4; ++r)
                            gt[w][mh * 16 + quad * 4 + r][nt * 16 + col] = acc[p * 2 + mh][nt][r];
                __syncthreads();
#pragma unroll
                for (int i = 0; i < 4; ++i) {
                    int idx  = i * 256 + tid;       // 1024 (m,cell) pairs per pass
                    int mloc = idx >> 5, cl = idx & 31;
                    int m    = p * 32 + mloc;
                    int cell = cellblk * 32 + cl;
                    float xi = gt[0][mloc][cl] + bd[cell];
                    float xf = gt[1][mloc][cl] + bd[4096 + cell];
                    float xg = gt[2][mloc][cl] + bd[8192 + cell];
                    float xo = gt[3][mloc][cl] + bd[12288 + cell];
                    float iv = sigm(xi), fv = sigm(xf), ov = sigm(xo);
                    float gv = tanhf(xg);
                    float cold = first ? 0.0f : c_reg[p * 4 + i];
                    float cn = fminf(fmaxf(iv * gv + fv * cold, -3.0f), 3.0f);
                    c_reg[p * 4 + i] = cn;
                    actb[((size_t)gdir * BB + m) * CC + cell] = f2bf(ov * tanhf(cn));
                    if (last) cs_l[(size_t)m * 8192 + gdir * 4096 + cell] = cn;
                }
                __syncthreads();
            }

            gridbar(cnt, gen);   // act visible to all

            // ---- projection: one 16x16 tile, K=4096 split over 4 waves ----
            const int ptt = pdir ? (TT - 1 - t) : t;
            const uint16_t* Arow = actb + ((size_t)pdir * BB + pbm * 16 + col) * CC + quad * 8;
            v4f pacc = {};
#pragma unroll
            for (int ki = 0; ki < 32; ++ki) {
                int ks = w * 32 + ki;
                v8bf a = *(const v8bf*)(Arow + (size_t)ks * 32);
                int byte = (col * 8192 + ks * 64 + quad * 16) ^ ((col & 7) << 4);
                v8bf b = *(const v8bf*)(lds + byte);
                pacc = __builtin_amdgcn_mfma_f32_16x16x32_bf16(a, b, pacc, 0, 0, 0);
            }
#pragma unroll
            for (int r = 0; r < 4; ++r)
                red[w * 256 + (quad * 4 + r) * 16 + col] = pacc[r];
            __syncthreads();
            float s = red[tid] + red[256 + tid] + red[512 + tid] + red[768 + tid];
            float h = fminf(fmaxf(s, -3.0f), 3.0f);
            int m = pbm * 16 + (tid >> 4), n = pbn * 16 + (tid & 15);
            // write bf16(0) at last step so next layer starts from h0=0
            hbuf[((size_t)pdir * BB + m) * HH + n] = last ? (uint16_t)0 : f2bf(h);
            if (l == 0) hseq[(((size_t)pdir * BB + m) * TT + ptt) * HH + n] = f2bf(h);
            size_t so = ((size_t)m * TT + ptt) * 1024 + (size_t)pdir * 512 + n;
            seq_l[so] = l ? (h + out[so]) : h;
            if (last) hs_l[(size_t)m * 1024 + pdir * 512 + n] = h;

            gridbar(cnt, gen);   // h visible before next step's gates
        }
    }
}

// ---------------- launch ----------------
extern "C" void kernel_launch(void* const* d_in, const int* in_sizes, int n_in,
                              void* d_out, int out_size, void* d_ws, size_t ws_size,
                              hipStream_t stream) {
    const float* x  = (const float*)d_in[0];
    const float* Wi = (const float*)d_in[1];
    const float* Wh = (const float*)d_in[2];
    const float* bb = (const float*)d_in[3];
    const float* Wp = (const float*)d_in[4];
    float* out = (float*)d_out;

    char* ws = (char*)d_ws;
    size_t off = 0;
    auto take = [&](size_t bytes) -> char* {
        char* p = ws + off;
        off = (off + bytes + 255) & ~(size_t)255;
        return p;
    };
    uint16_t* Wf   = (uint16_t*)take(2ull * 2 * 16384 * 1024 * 2); // 134 MB
    uint16_t* Wpb  = (uint16_t*)take(2ull * 2 * 512 * 4096 * 2);   // 16.8 MB
    uint16_t* xb   = (uint16_t*)take((size_t)BB * TT * DD * 2);    // 8.4 MB
    uint16_t* hseq = (uint16_t*)take(2ull * BB * TT * HH * 2);     // 16.8 MB
    uint16_t* hbuf = (uint16_t*)take(2ull * BB * HH * 2);
    uint16_t* actb = (uint16_t*)take(2ull * BB * CC * 2);
    unsigned* bar  = (unsigned*)take(256);

    hipLaunchKernelGGL(k_conv_wfull, dim3(32768), dim3(256), 0, stream, Wi, Wh, Wf);
    hipLaunchKernelGGL(k_conv_plain, dim3(4096), dim3(256), 0, stream, Wp, Wpb,
                       2 * 2 * 512 * 4096 / 8);
    hipLaunchKernelGGL(k_conv_plain, dim3(2048), dim3(256), 0, stream, x, xb,
                       BB * TT * DD / 8);
    hipLaunchKernelGGL(k_init, dim3(32), dim3(256), 0, stream, hbuf, bar);

    const uint16_t* Wf_c  = Wf;
    const float*    bb_c  = bb;
    const uint16_t* Wpb_c = Wpb;
    const uint16_t* xb_c  = xb;
    void* args[] = { (void*)&Wf_c, (void*)&bb_c, (void*)&Wpb_c, (void*)&xb_c,
                     (void*)&hseq, (void*)&hbuf, (void*)&actb, (void*)&out,
                     (void*)&bar };
    hipError_t e = hipLaunchCooperativeKernel((const void*)k_elmo, dim3(NBLK),
                                              dim3(256), args, 0, stream);
    if (e != hipSuccess) {
        // 256 blocks x 1 block/CU on a 256-CU device: co-resident under a
        // plain launch too; the barrier only needs co-residency.
        hipLaunchKernelGGL(k_elmo, dim3(NBLK), dim3(256), 0, stream,
                           Wf_c, bb_c, Wpb_c, xb_c, hseq, hbuf, actb, out, bar);
    }
}

// Round 3
// 14144.557 us; speedup vs baseline: 1.0090x; 1.0090x over previous
//
#include <hip/hip_runtime.h>
#include <hip/hip_bf16.h>
#include <stdint.h>
#include <math.h>

// ElmoLstm on MI355X — persistent kernel, v3.
// 256 blocks x 512 thr (8 waves, 2/SIMD). Wave w = (gate w>>1, K-half w&1):
// 32 cells x K=512 of [Wh|Wi] in 128 VGPRs -> true register residency.
// Wp tile in LDS (128 KB, xor-swizzled). c-state in registers.
// Two-level grid barrier (8x32 + 8 arrivals), two barriers per step.

#define BB 64
#define TT 128
#define DD 512
#define HH 512
#define CC 4096
#define NBLK 256
#define GT_STRIDE 34
#define GT_FLOATS (4 * 16 * GT_STRIDE)          // one partial buffer: 2176 floats
#define LDS_BYTES (131072 + 2 * GT_FLOATS * 4)  // 148480

typedef __bf16 v8bf __attribute__((ext_vector_type(8)));
typedef float  v4f  __attribute__((ext_vector_type(4)));
typedef short  v8s  __attribute__((ext_vector_type(8)));

__device__ __forceinline__ uint16_t f2bf(float f) {
    unsigned int x = __float_as_uint(f);
    unsigned int r = (x + 0x7fffu + ((x >> 16) & 1u)) >> 16;
    return (uint16_t)r;
}
__device__ __forceinline__ float sigm(float x) { return 1.0f / (1.0f + __expf(-x)); }

// ---------------- weight conversion ----------------
__global__ __launch_bounds__(256) void k_conv_wfull(
        const float* __restrict__ Wi, const float* __restrict__ Wh,
        uint16_t* __restrict__ Wf) {
    size_t i   = (size_t)blockIdx.x * blockDim.x + threadIdx.x;
    size_t idx = i * 8;
    size_t row = idx >> 10;
    int    k   = (int)(idx & 1023);
    const float* s = (k < 512) ? (Wh + row * 512 + k) : (Wi + row * 512 + (k - 512));
    float4 f0 = ((const float4*)s)[0];
    float4 f1 = ((const float4*)s)[1];
    v8s v;
    v[0]=f2bf(f0.x); v[1]=f2bf(f0.y); v[2]=f2bf(f0.z); v[3]=f2bf(f0.w);
    v[4]=f2bf(f1.x); v[5]=f2bf(f1.y); v[6]=f2bf(f1.z); v[7]=f2bf(f1.w);
    ((v8s*)Wf)[i] = v;
}

__global__ __launch_bounds__(256) void k_conv_plain(
        const float* __restrict__ src, uint16_t* __restrict__ dst, int n8) {
    int i = blockIdx.x * blockDim.x + threadIdx.x;
    if (i >= n8) return;
    const float4* s = (const float4*)(src + (size_t)i * 8);
    float4 f0 = s[0];
    float4 f1 = s[1];
    v8s v;
    v[0]=f2bf(f0.x); v[1]=f2bf(f0.y); v[2]=f2bf(f0.z); v[3]=f2bf(f0.w);
    v[4]=f2bf(f1.x); v[5]=f2bf(f1.y); v[6]=f2bf(f1.z); v[7]=f2bf(f1.w);
    ((v8s*)dst)[i] = v;
}

// ---------------- init: zero h0 + barrier state ----------------
__global__ __launch_bounds__(256) void k_init(uint16_t* __restrict__ hbuf,
                                              unsigned* __restrict__ bar) {
    int idx = blockIdx.x * 256 + threadIdx.x;
    if (idx < 8192) ((int4*)hbuf)[idx] = make_int4(0, 0, 0, 0);
    if (blockIdx.x == 0) bar[threadIdx.x] = 0;   // 256 uints
}

// ---------------- two-level grid barrier (sense via generation) ------------
// bar[x*16] x=0..7: per-group counters; bar[128]: group count; bar[144]: gen.
__device__ __forceinline__ void gridbar(unsigned* bar) {
    __syncthreads();
    if (threadIdx.x == 0) {
        unsigned* cntx = bar + ((blockIdx.x & 7) << 4);
        unsigned* gcnt = bar + 128;
        unsigned* gen  = bar + 144;
        unsigned g = __hip_atomic_load(gen, __ATOMIC_RELAXED, __HIP_MEMORY_SCOPE_AGENT);
        unsigned a = __hip_atomic_fetch_add(cntx, 1u, __ATOMIC_ACQ_REL, __HIP_MEMORY_SCOPE_AGENT);
        if (a == 31u) {
            __hip_atomic_store(cntx, 0u, __ATOMIC_RELAXED, __HIP_MEMORY_SCOPE_AGENT);
            unsigned b = __hip_atomic_fetch_add(gcnt, 1u, __ATOMIC_ACQ_REL, __HIP_MEMORY_SCOPE_AGENT);
            if (b == 7u) {
                __hip_atomic_store(gcnt, 0u, __ATOMIC_RELAXED, __HIP_MEMORY_SCOPE_AGENT);
                __hip_atomic_fetch_add(gen, 1u, __ATOMIC_ACQ_REL, __HIP_MEMORY_SCOPE_AGENT);
            } else {
                while (__hip_atomic_load(gen, __ATOMIC_RELAXED, __HIP_MEMORY_SCOPE_AGENT) == g)
                    __builtin_amdgcn_s_sleep(2);
                __builtin_amdgcn_fence(__ATOMIC_ACQUIRE, "agent");
            }
        } else {
            while (__hip_atomic_load(gen, __ATOMIC_RELAXED, __HIP_MEMORY_SCOPE_AGENT) == g)
                __builtin_amdgcn_s_sleep(2);
            __builtin_amdgcn_fence(__ATOMIC_ACQUIRE, "agent");
        }
    }
    __syncthreads();
}

// ---------------- persistent ELMo LSTM ----------------
__global__ __launch_bounds__(512, 2) void k_elmo(
        const uint16_t* __restrict__ Wf,    // [2][2][16384][1024] bf16
        const float*    __restrict__ bias,  // [2][2][16384]
        const uint16_t* __restrict__ Wpb,   // [2][2][512][4096] bf16
        const uint16_t* __restrict__ xb,    // [64][128][512] bf16
        uint16_t* __restrict__ hseq,        // [2][64][128][512] bf16
        uint16_t* __restrict__ hbuf,        // [2][64][512] bf16
        uint16_t* __restrict__ actb,        // [2][64][4096] bf16
        float*    __restrict__ out,
        unsigned* __restrict__ bar) {
    const int tid  = threadIdx.x;
    const int w    = tid >> 6;
    const int lane = tid & 63;
    const int col  = lane & 15;
    const int quad = lane >> 4;
    const int g    = w >> 1;        // gate group 0..3
    const int dlt  = w & 1;         // K-half: 0 = h-part, 1 = x-part
    const int bx   = blockIdx.x;
    const int gdir = bx >> 7, cellblk = bx & 127;
    const int xcd  = bx & 7,  rr = bx >> 3;
    const int pdir = xcd >> 2, pbm = xcd & 3, pbn = rr;

    __shared__ __attribute__((aligned(128))) char lds[LDS_BYTES]; // [0,131072): Wp
    float* gtA = (float*)(lds + 131072);            // [4][16][34] h-half partials
    float* gtB = gtA + GT_FLOATS;                   // x-half partials
    float* red = (float*)(lds + 131072);            // proj reduce (disjoint phase)

    const size_t SEQ = (size_t)BB * TT * 1024;
    float* hs_base = out + 2 * SEQ;
    float* cs_base = hs_base + 2ull * BB * 1024;

    float c_reg[4];
    v8bf  wreg[2][16];                              // 128 VGPRs of gate weights

    for (int l = 0; l < 2; ++l) {
        const uint16_t* Wl   = Wf + (size_t)l * 2 * 16384 * 1024;
        const float*    bd   = bias + ((size_t)l * 2 + gdir) * 16384;
        const uint16_t* Wpl  = Wpb + ((size_t)l * 2 + pdir) * 512 * 4096;
        const uint16_t* xsrc = l ? (hseq + (size_t)gdir * BB * TT * HH) : xb;
        float* seq_l = out + (size_t)l * SEQ;
        float* hs_l  = hs_base + (size_t)l * BB * 1024;
        float* cs_l  = cs_base + (size_t)l * BB * 8192;

        // ---- gate-weight fragments: 32 cells x K-half, once per layer ----
#pragma unroll
        for (int nt = 0; nt < 2; ++nt) {
            int j = g * 4096 + cellblk * 32 + nt * 16 + col;
            const uint16_t* rp = Wl + ((size_t)gdir * 16384 + j) * 1024 + dlt * 512 + quad * 8;
#pragma unroll
            for (int ks = 0; ks < 16; ++ks)
                wreg[nt][ks] = *(const v8bf*)(rp + ks * 32);
        }
        // ---- Wp tile -> LDS, xor-swizzled, once per layer ----
        for (int c8 = tid; c8 < 8192; c8 += 512) {
            int row = c8 >> 9;
            int off = (c8 & 511) << 4;
            const uint16_t* src = Wpl + (size_t)(pbn * 16 + row) * 4096 + (off >> 1);
            v8s v = *(const v8s*)src;
            *(v8s*)(lds + ((row * 8192 + off) ^ ((row & 7) << 4))) = v;
        }
        __syncthreads();

        for (int t = 0; t < TT; ++t) {
            const bool first = (t == 0), last = (t == TT - 1);
            const int gtt = gdir ? (TT - 1 - t) : t;

            // ---- gates: this wave's K-half only ----
            v4f acc[4][2] = {};
            const uint16_t* hA = hbuf + (size_t)gdir * BB * HH;
#pragma unroll
            for (int ks = 0; ks < 16; ++ks) {
                int k = ks * 32 + quad * 8;
                v8bf a[4];
                if (dlt == 0) {
#pragma unroll
                    for (int mt = 0; mt < 4; ++mt)
                        a[mt] = *(const v8bf*)(hA + (size_t)(mt * 16 + col) * HH + k);
                } else {
#pragma unroll
                    for (int mt = 0; mt < 4; ++mt)
                        a[mt] = *(const v8bf*)(xsrc + ((size_t)(mt * 16 + col) * TT + gtt) * DD + k);
                }
#pragma unroll
                for (int mt = 0; mt < 4; ++mt)
#pragma unroll
                    for (int nt = 0; nt < 2; ++nt)
                        acc[mt][nt] = __builtin_amdgcn_mfma_f32_16x16x32_bf16(
                                a[mt], wreg[nt][ks], acc[mt][nt], 0, 0, 0);
            }

            // ---- cell epilogue: 4 m-quarter passes, sum the two K-halves ----
#pragma unroll
            for (int p = 0; p < 4; ++p) {
                float* dst = dlt ? gtB : gtA;
#pragma unroll
                for (int nt = 0; nt < 2; ++nt)
#pragma unroll
                    for (int r = 0; r < 4; ++r)
                        dst[g * (16 * GT_STRIDE) + (quad * 4 + r) * GT_STRIDE + nt * 16 + col]
                            = acc[p][nt][r];
                __syncthreads();
                {
                    int mloc = tid >> 5, cl = tid & 31;     // 512 (m,cell) pairs
                    int m    = p * 16 + mloc;
                    int cell = cellblk * 32 + cl;
                    int e0 = mloc * GT_STRIDE + cl;
                    float xi = gtA[e0]                    + gtB[e0]                    + bd[cell];
                    float xf = gtA[e0 + 16 * GT_STRIDE]   + gtB[e0 + 16 * GT_STRIDE]   + bd[4096 + cell];
                    float xg = gtA[e0 + 32 * GT_STRIDE]   + gtB[e0 + 32 * GT_STRIDE]   + bd[8192 + cell];
                    float xo = gtA[e0 + 48 * GT_STRIDE]   + gtB[e0 + 48 * GT_STRIDE]   + bd[12288 + cell];
                    float iv = sigm(xi), fv = sigm(xf), ov = sigm(xo);
                    float gv = tanhf(xg);
                    float cold = first ? 0.0f : c_reg[p];
                    float cn = fminf(fmaxf(iv * gv + fv * cold, -3.0f), 3.0f);
                    c_reg[p] = cn;
                    actb[((size_t)gdir * BB + m) * CC + cell] = f2bf(ov * tanhf(cn));
                    if (last) cs_l[(size_t)m * 8192 + gdir * 4096 + cell] = cn;
                }
                __syncthreads();
            }

            gridbar(bar);   // act visible to all

            // ---- projection: 16x16 tile, K=4096 over 8 waves ----
            const int ptt = pdir ? (TT - 1 - t) : t;
            const uint16_t* Arow = actb + ((size_t)pdir * BB + pbm * 16 + col) * CC + quad * 8;
            v4f pacc = {};
#pragma unroll
            for (int ki = 0; ki < 16; ++ki) {
                int ks = w * 16 + ki;
                v8bf a = *(const v8bf*)(Arow + (size_t)ks * 32);
                int byte = (col * 8192 + ks * 64 + quad * 16) ^ ((col & 7) << 4);
                v8bf b = *(const v8bf*)(lds + byte);
                pacc = __builtin_amdgcn_mfma_f32_16x16x32_bf16(a, b, pacc, 0, 0, 0);
            }
#pragma unroll
            for (int r = 0; r < 4; ++r)
                red[w * 256 + (quad * 4 + r) * 16 + col] = pacc[r];
            __syncthreads();
            if (tid < 256) {
                float s = 0.0f;
#pragma unroll
                for (int j = 0; j < 8; ++j) s += red[j * 256 + tid];
                float h = fminf(fmaxf(s, -3.0f), 3.0f);
                int m = pbm * 16 + (tid >> 4), n = pbn * 16 + (tid & 15);
                hbuf[((size_t)pdir * BB + m) * HH + n] = last ? (uint16_t)0 : f2bf(h);
                if (l == 0) hseq[(((size_t)pdir * BB + m) * TT + ptt) * HH + n] = f2bf(h);
                size_t so = ((size_t)m * TT + ptt) * 1024 + (size_t)pdir * 512 + n;
                seq_l[so] = l ? (h + out[so]) : h;
                if (last) hs_l[(size_t)m * 1024 + pdir * 512 + n] = h;
            }

            gridbar(bar);   // h visible before next step's gates
        }
    }
}

// ---------------- launch ----------------
extern "C" void kernel_launch(void* const* d_in, const int* in_sizes, int n_in,
                              void* d_out, int out_size, void* d_ws, size_t ws_size,
                              hipStream_t stream) {
    const float* x  = (const float*)d_in[0];
    const float* Wi = (const float*)d_in[1];
    const float* Wh = (const float*)d_in[2];
    const float* bb = (const float*)d_in[3];
    const float* Wp = (const float*)d_in[4];
    float* out = (float*)d_out;

    char* ws = (char*)d_ws;
    size_t off = 0;
    auto take = [&](size_t bytes) -> char* {
        char* p = ws + off;
        off = (off + bytes + 255) & ~(size_t)255;
        return p;
    };
    uint16_t* Wf   = (uint16_t*)take(2ull * 2 * 16384 * 1024 * 2); // 134 MB
    uint16_t* Wpb  = (uint16_t*)take(2ull * 2 * 512 * 4096 * 2);   // 16.8 MB
    uint16_t* xb   = (uint16_t*)take((size_t)BB * TT * DD * 2);    // 8.4 MB
    uint16_t* hseq = (uint16_t*)take(2ull * BB * TT * HH * 2);     // 16.8 MB
    uint16_t* hbuf = (uint16_t*)take(2ull * BB * HH * 2);
    uint16_t* actb = (uint16_t*)take(2ull * BB * CC * 2);
    unsigned* bar  = (unsigned*)take(1024);

    hipLaunchKernelGGL(k_conv_wfull, dim3(32768), dim3(256), 0, stream, Wi, Wh, Wf);
    hipLaunchKernelGGL(k_conv_plain, dim3(4096), dim3(256), 0, stream, Wp, Wpb,
                       2 * 2 * 512 * 4096 / 8);
    hipLaunchKernelGGL(k_conv_plain, dim3(2048), dim3(256), 0, stream, x, xb,
                       BB * TT * DD / 8);
    hipLaunchKernelGGL(k_init, dim3(32), dim3(256), 0, stream, hbuf, bar);

    const uint16_t* Wf_c  = Wf;
    const float*    bb_c  = bb;
    const uint16_t* Wpb_c = Wpb;
    const uint16_t* xb_c  = xb;
    void* args[] = { (void*)&Wf_c, (void*)&bb_c, (void*)&Wpb_c, (void*)&xb_c,
                     (void*)&hseq, (void*)&hbuf, (void*)&actb, (void*)&out,
                     (void*)&bar };
    hipError_t e = hipLaunchCooperativeKernel((const void*)k_elmo, dim3(NBLK),
                                              dim3(512), args, 0, stream);
    if (e != hipSuccess) {
        // 256 blocks x 1 block/CU on 256 CUs: co-resident under plain launch;
        // the barrier only needs co-residency.
        hipLaunchKernelGGL(k_elmo, dim3(NBLK), dim3(512), 0, stream,
                           Wf_c, bb_c, Wpb_c, xb_c, hseq, hbuf, actb, out, bar);
    }
}

// Round 5
// 14104.773 us; speedup vs baseline: 1.0118x; 1.0028x over previous
//
#include <hip/hip_runtime.h>
#include <hip/hip_bf16.h>
#include <stdint.h>
#include <math.h>

// ElmoLstm on MI355X — persistent kernel, v4b.
// 256 blocks x 512 thr (8 waves, 2/SIMD via amdgpu_waves_per_eu(2)).
// Wave w = (gate w>>1, K-half w&1): 32 cells x K=512 of [Wh|Wi] in 128 VGPRs,
// made opaque via asm so the compiler cannot rematerialize the loads (the
// round-3 failure mode: 128-VGPR allocation re-streamed 9.4 GB of weights).
// Wp tile in LDS (128 KB, xor-swizzled). c-state in registers.
// Two-level grid barrier (8x32 + 8 arrivals), two barriers per step.

#define BB 64
#define TT 128
#define DD 512
#define HH 512
#define CC 4096
#define NBLK 256
#define GT_STRIDE 34
#define GT_FLOATS (4 * 16 * GT_STRIDE)          // one partial buffer: 2176 floats
#define LDS_BYTES (131072 + 2 * GT_FLOATS * 4)  // 148480

typedef __bf16 v8bf __attribute__((ext_vector_type(8)));
typedef float  v4f  __attribute__((ext_vector_type(4)));
typedef short  v8s  __attribute__((ext_vector_type(8)));

__device__ __forceinline__ uint16_t f2bf(float f) {
    unsigned int x = __float_as_uint(f);
    unsigned int r = (x + 0x7fffu + ((x >> 16) & 1u)) >> 16;
    return (uint16_t)r;
}
__device__ __forceinline__ float sigm(float x) { return 1.0f / (1.0f + __expf(-x)); }

// ---------------- weight conversion ----------------
__global__ __launch_bounds__(256) void k_conv_wfull(
        const float* __restrict__ Wi, const float* __restrict__ Wh,
        uint16_t* __restrict__ Wf) {
    size_t i   = (size_t)blockIdx.x * blockDim.x + threadIdx.x;
    size_t idx = i * 8;
    size_t row = idx >> 10;
    int    k   = (int)(idx & 1023);
    const float* s = (k < 512) ? (Wh + row * 512 + k) : (Wi + row * 512 + (k - 512));
    float4 f0 = ((const float4*)s)[0];
    float4 f1 = ((const float4*)s)[1];
    v8s v;
    v[0]=f2bf(f0.x); v[1]=f2bf(f0.y); v[2]=f2bf(f0.z); v[3]=f2bf(f0.w);
    v[4]=f2bf(f1.x); v[5]=f2bf(f1.y); v[6]=f2bf(f1.z); v[7]=f2bf(f1.w);
    ((v8s*)Wf)[i] = v;
}

__global__ __launch_bounds__(256) void k_conv_plain(
        const float* __restrict__ src, uint16_t* __restrict__ dst, int n8) {
    int i = blockIdx.x * blockDim.x + threadIdx.x;
    if (i >= n8) return;
    const float4* s = (const float4*)(src + (size_t)i * 8);
    float4 f0 = s[0];
    float4 f1 = s[1];
    v8s v;
    v[0]=f2bf(f0.x); v[1]=f2bf(f0.y); v[2]=f2bf(f0.z); v[3]=f2bf(f0.w);
    v[4]=f2bf(f1.x); v[5]=f2bf(f1.y); v[6]=f2bf(f1.z); v[7]=f2bf(f1.w);
    ((v8s*)dst)[i] = v;
}

// ---------------- init: zero h0 + barrier state ----------------
__global__ __launch_bounds__(256) void k_init(uint16_t* __restrict__ hbuf,
                                              unsigned* __restrict__ bar) {
    int idx = blockIdx.x * 256 + threadIdx.x;
    if (idx < 8192) ((int4*)hbuf)[idx] = make_int4(0, 0, 0, 0);
    if (blockIdx.x == 0) bar[threadIdx.x] = 0;   // 256 uints
}

// ---------------- two-level grid barrier (sense via generation) ------------
// bar[x*16] x=0..7: per-group counters; bar[128]: group count; bar[144]: gen.
__device__ __forceinline__ void gridbar(unsigned* bar) {
    __syncthreads();
    if (threadIdx.x == 0) {
        unsigned* cntx = bar + ((blockIdx.x & 7) << 4);
        unsigned* gcnt = bar + 128;
        unsigned* gen  = bar + 144;
        unsigned g = __hip_atomic_load(gen, __ATOMIC_RELAXED, __HIP_MEMORY_SCOPE_AGENT);
        unsigned a = __hip_atomic_fetch_add(cntx, 1u, __ATOMIC_ACQ_REL, __HIP_MEMORY_SCOPE_AGENT);
        if (a == 31u) {
            __hip_atomic_store(cntx, 0u, __ATOMIC_RELAXED, __HIP_MEMORY_SCOPE_AGENT);
            unsigned b = __hip_atomic_fetch_add(gcnt, 1u, __ATOMIC_ACQ_REL, __HIP_MEMORY_SCOPE_AGENT);
            if (b == 7u) {
                __hip_atomic_store(gcnt, 0u, __ATOMIC_RELAXED, __HIP_MEMORY_SCOPE_AGENT);
                __hip_atomic_fetch_add(gen, 1u, __ATOMIC_ACQ_REL, __HIP_MEMORY_SCOPE_AGENT);
            } else {
                while (__hip_atomic_load(gen, __ATOMIC_RELAXED, __HIP_MEMORY_SCOPE_AGENT) == g)
                    __builtin_amdgcn_s_sleep(2);
                __builtin_amdgcn_fence(__ATOMIC_ACQUIRE, "agent");
            }
        } else {
            while (__hip_atomic_load(gen, __ATOMIC_RELAXED, __HIP_MEMORY_SCOPE_AGENT) == g)
                __builtin_amdgcn_s_sleep(2);
            __builtin_amdgcn_fence(__ATOMIC_ACQUIRE, "agent");
        }
    }
    __syncthreads();
}

// ---------------- persistent ELMo LSTM ----------------
__global__ __attribute__((amdgpu_waves_per_eu(2))) __launch_bounds__(512)
void k_elmo(
        const uint16_t* __restrict__ Wf,    // [2][2][16384][1024] bf16
        const float*    __restrict__ bias,  // [2][2][16384]
        const uint16_t* __restrict__ Wpb,   // [2][2][512][4096] bf16
        const uint16_t* __restrict__ xb,    // [64][128][512] bf16
        uint16_t* __restrict__ hseq,        // [2][64][128][512] bf16
        uint16_t* __restrict__ hbuf,        // [2][64][512] bf16
        uint16_t* __restrict__ actb,        // [2][64][4096] bf16
        float*    __restrict__ out,
        unsigned* __restrict__ bar) {
    const int tid  = threadIdx.x;
    const int w    = tid >> 6;
    const int lane = tid & 63;
    const int col  = lane & 15;
    const int quad = lane >> 4;
    const int g    = w >> 1;        // gate group 0..3
    const int dlt  = w & 1;         // K-half: 0 = h-part, 1 = x-part
    const int bx   = blockIdx.x;
    const int gdir = bx >> 7, cellblk = bx & 127;
    const int xcd  = bx & 7,  rr = bx >> 3;
    const int pdir = xcd >> 2, pbm = xcd & 3, pbn = rr;

    __shared__ __attribute__((aligned(128))) char lds[LDS_BYTES]; // [0,131072): Wp
    float* gtA = (float*)(lds + 131072);            // [4][16][34] h-half partials
    float* gtB = gtA + GT_FLOATS;                   // x-half partials
    float* red = (float*)(lds + 131072);            // proj reduce (disjoint phase)

    const size_t SEQ = (size_t)BB * TT * 1024;
    float* hs_base = out + 2 * SEQ;
    float* cs_base = hs_base + 2ull * BB * 1024;

    float c_reg[4];
    v8bf  wreg[2][16];                              // 128 VGPRs of gate weights

    for (int l = 0; l < 2; ++l) {
        const uint16_t* Wl   = Wf + (size_t)l * 2 * 16384 * 1024;
        const float*    bd   = bias + ((size_t)l * 2 + gdir) * 16384;
        const uint16_t* Wpl  = Wpb + ((size_t)l * 2 + pdir) * 512 * 4096;
        const uint16_t* xsrc = l ? (hseq + (size_t)gdir * BB * TT * HH) : xb;
        float* seq_l = out + (size_t)l * SEQ;
        float* hs_l  = hs_base + (size_t)l * BB * 1024;
        float* cs_l  = cs_base + (size_t)l * BB * 8192;

        // ---- gate-weight fragments: 32 cells x K-half, once per layer ----
#pragma unroll
        for (int nt = 0; nt < 2; ++nt) {
            int j = g * 4096 + cellblk * 32 + nt * 16 + col;
            const uint16_t* rp = Wl + ((size_t)gdir * 16384 + j) * 1024 + dlt * 512 + quad * 8;
#pragma unroll
            for (int ks = 0; ks < 16; ++ks)
                wreg[nt][ks] = *(const v8bf*)(rp + ks * 32);
        }
        // make the weight values opaque: cannot be rematerialized by reloading
#pragma unroll
        for (int nt = 0; nt < 2; ++nt)
#pragma unroll
            for (int ks = 0; ks < 16; ++ks)
                asm volatile("" : "+v"(wreg[nt][ks]));

        // ---- Wp tile -> LDS, xor-swizzled, once per layer ----
        for (int c8 = tid; c8 < 8192; c8 += 512) {
            int row = c8 >> 9;
            int off = (c8 & 511) << 4;
            const uint16_t* src = Wpl + (size_t)(pbn * 16 + row) * 4096 + (off >> 1);
            v8s v = *(const v8s*)src;
            *(v8s*)(lds + ((row * 8192 + off) ^ ((row & 7) << 4))) = v;
        }
        __syncthreads();

        for (int t = 0; t < TT; ++t) {
            const bool first = (t == 0), last = (t == TT - 1);
            const int gtt = gdir ? (TT - 1 - t) : t;

            // ---- gates: this wave's K-half only ----
            v4f acc[4][2] = {};
            const uint16_t* hA = hbuf + (size_t)gdir * BB * HH;
#pragma unroll
            for (int ks = 0; ks < 16; ++ks) {
                int k = ks * 32 + quad * 8;
                v8bf a[4];
                if (dlt == 0) {
#pragma unroll
                    for (int mt = 0; mt < 4; ++mt)
                        a[mt] = *(const v8bf*)(hA + (size_t)(mt * 16 + col) * HH + k);
                } else {
#pragma unroll
                    for (int mt = 0; mt < 4; ++mt)
                        a[mt] = *(const v8bf*)(xsrc + ((size_t)(mt * 16 + col) * TT + gtt) * DD + k);
                }
#pragma unroll
                for (int mt = 0; mt < 4; ++mt)
#pragma unroll
                    for (int nt = 0; nt < 2; ++nt)
                        acc[mt][nt] = __builtin_amdgcn_mfma_f32_16x16x32_bf16(
                                a[mt], wreg[nt][ks], acc[mt][nt], 0, 0, 0);
            }

            // ---- cell epilogue: 4 m-quarter passes, sum the two K-halves ----
#pragma unroll
            for (int p = 0; p < 4; ++p) {
                float* dst = dlt ? gtB : gtA;
#pragma unroll
                for (int nt = 0; nt < 2; ++nt)
#pragma unroll
                    for (int r = 0; r < 4; ++r)
                        dst[g * (16 * GT_STRIDE) + (quad * 4 + r) * GT_STRIDE + nt * 16 + col]
                            = acc[p][nt][r];
                __syncthreads();
                {
                    int mloc = tid >> 5, cl = tid & 31;     // 512 (m,cell) pairs
                    int m    = p * 16 + mloc;
                    int cell = cellblk * 32 + cl;
                    int e0 = mloc * GT_STRIDE + cl;
                    float xi = gtA[e0]                    + gtB[e0]                    + bd[cell];
                    float xf = gtA[e0 + 16 * GT_STRIDE]   + gtB[e0 + 16 * GT_STRIDE]   + bd[4096 + cell];
                    float xg = gtA[e0 + 32 * GT_STRIDE]   + gtB[e0 + 32 * GT_STRIDE]   + bd[8192 + cell];
                    float xo = gtA[e0 + 48 * GT_STRIDE]   + gtB[e0 + 48 * GT_STRIDE]   + bd[12288 + cell];
                    float iv = sigm(xi), fv = sigm(xf), ov = sigm(xo);
                    float gv = tanhf(xg);
                    float cold = first ? 0.0f : c_reg[p];
                    float cn = fminf(fmaxf(iv * gv + fv * cold, -3.0f), 3.0f);
                    c_reg[p] = cn;
                    actb[((size_t)gdir * BB + m) * CC + cell] = f2bf(ov * tanhf(cn));
                    if (last) cs_l[(size_t)m * 8192 + gdir * 4096 + cell] = cn;
                }
                __syncthreads();
            }

            gridbar(bar);   // act visible to all

            // ---- projection: 16x16 tile, K=4096 over 8 waves ----
            const int ptt = pdir ? (TT - 1 - t) : t;
            const uint16_t* Arow = actb + ((size_t)pdir * BB + pbm * 16 + col) * CC + quad * 8;
            v4f pacc = {};
#pragma unroll
            for (int ki = 0; ki < 16; ++ki) {
                int ks = w * 16 + ki;
                v8bf a = *(const v8bf*)(Arow + (size_t)ks * 32);
                int byte = (col * 8192 + ks * 64 + quad * 16) ^ ((col & 7) << 4);
                v8bf b = *(const v8bf*)(lds + byte);
                pacc = __builtin_amdgcn_mfma_f32_16x16x32_bf16(a, b, pacc, 0, 0, 0);
            }
#pragma unroll
            for (int r = 0; r < 4; ++r)
                red[w * 256 + (quad * 4 + r) * 16 + col] = pacc[r];
            __syncthreads();
            if (tid < 256) {
                float s = 0.0f;
#pragma unroll
                for (int j = 0; j < 8; ++j) s += red[j * 256 + tid];
                float h = fminf(fmaxf(s, -3.0f), 3.0f);
                int m = pbm * 16 + (tid >> 4), n = pbn * 16 + (tid & 15);
                hbuf[((size_t)pdir * BB + m) * HH + n] = last ? (uint16_t)0 : f2bf(h);
                if (l == 0) hseq[(((size_t)pdir * BB + m) * TT + ptt) * HH + n] = f2bf(h);
                size_t so = ((size_t)m * TT + ptt) * 1024 + (size_t)pdir * 512 + n;
                seq_l[so] = l ? (h + out[so]) : h;
                if (last) hs_l[(size_t)m * 1024 + pdir * 512 + n] = h;
            }

            gridbar(bar);   // h visible before next step's gates
        }
    }
}

// ---------------- launch ----------------
extern "C" void kernel_launch(void* const* d_in, const int* in_sizes, int n_in,
                              void* d_out, int out_size, void* d_ws, size_t ws_size,
                              hipStream_t stream) {
    const float* x  = (const float*)d_in[0];
    const float* Wi = (const float*)d_in[1];
    const float* Wh = (const float*)d_in[2];
    const float* bb = (const float*)d_in[3];
    const float* Wp = (const float*)d_in[4];
    float* out = (float*)d_out;

    char* ws = (char*)d_ws;
    size_t off = 0;
    auto take = [&](size_t bytes) -> char* {
        char* p = ws + off;
        off = (off + bytes + 255) & ~(size_t)255;
        return p;
    };
    uint16_t* Wf   = (uint16_t*)take(2ull * 2 * 16384 * 1024 * 2); // 134 MB
    uint16_t* Wpb  = (uint16_t*)take(2ull * 2 * 512 * 4096 * 2);   // 16.8 MB
    uint16_t* xb   = (uint16_t*)take((size_t)BB * TT * DD * 2);    // 8.4 MB
    uint16_t* hseq = (uint16_t*)take(2ull * BB * TT * HH * 2);     // 16.8 MB
    uint16_t* hbuf = (uint16_t*)take(2ull * BB * HH * 2);
    uint16_t* actb = (uint16_t*)take(2ull * BB * CC * 2);
    unsigned* bar  = (unsigned*)take(1024);

    hipLaunchKernelGGL(k_conv_wfull, dim3(32768), dim3(256), 0, stream, Wi, Wh, Wf);
    hipLaunchKernelGGL(k_conv_plain, dim3(4096), dim3(256), 0, stream, Wp, Wpb,
                       2 * 2 * 512 * 4096 / 8);
    hipLaunchKernelGGL(k_conv_plain, dim3(2048), dim3(256), 0, stream, x, xb,
                       BB * TT * DD / 8);
    hipLaunchKernelGGL(k_init, dim3(32), dim3(256), 0, stream, hbuf, bar);

    const uint16_t* Wf_c  = Wf;
    const float*    bb_c  = bb;
    const uint16_t* Wpb_c = Wpb;
    const uint16_t* xb_c  = xb;
    void* args[] = { (void*)&Wf_c, (void*)&bb_c, (void*)&Wpb_c, (void*)&xb_c,
                     (void*)&hseq, (void*)&hbuf, (void*)&actb, (void*)&out,
                     (void*)&bar };
    hipError_t e = hipLaunchCooperativeKernel((const void*)k_elmo, dim3(NBLK),
                                              dim3(512), args, 0, stream);
    if (e != hipSuccess) {
        // 256 blocks x 1 block/CU on 256 CUs: co-resident under plain launch;
        // the barrier only needs co-residency.
        hipLaunchKernelGGL(k_elmo, dim3(NBLK), dim3(512), 0, stream,
                           Wf_c, bb_c, Wpb_c, xb_c, hseq, hbuf, actb, out, bar);
    }
}